// Round 16
// baseline (1036.937 us; speedup 1.0000x reference)
//
#include <hip/hip_runtime.h>
#include <hip/hip_bf16.h>
#include <cstdint>

#define N_ROWS 131072   // 32*4096
#define DDIM   128
#define KCODE  512
#define TMR    128      // rows per block in K1 (4 waves x 32 rows)
#define NCT    32       // code tiles of 16
#define EPS_W  0.05f    // rescore window (>> 2x bf16-split dot error bound)

typedef __attribute__((ext_vector_type(8))) short short8;
typedef __attribute__((ext_vector_type(4))) float f32x4;

// ---------------- threefry2x32 (JAX-compatible) ----------------
__device__ __forceinline__ uint32_t rotl32(uint32_t x, uint32_t n) {
    return (x << n) | (x >> (32 - n));
}
__device__ __forceinline__ void threefry2x32(uint32_t k0, uint32_t k1,
                                             uint32_t x0, uint32_t x1,
                                             uint32_t& o0, uint32_t& o1) {
    uint32_t ks[3] = {k0, k1, k0 ^ k1 ^ 0x1BD11BDAu};
    x0 += ks[0]; x1 += ks[1];
    const uint32_t rA[4] = {13, 15, 26, 6};
    const uint32_t rB[4] = {17, 29, 16, 24};
#pragma unroll
    for (int i = 0; i < 5; ++i) {
        const uint32_t* r = (i & 1) ? rB : rA;
#pragma unroll
        for (int j = 0; j < 4; ++j) { x0 += x1; x1 = rotl32(x1, r[j]); x1 ^= x0; }
        x0 += ks[(i + 1) % 3];
        x1 += ks[(i + 2) % 3] + (uint32_t)(i + 1);
    }
    o0 = x0; o1 = x1;
}
__device__ __forceinline__ uint32_t jax_randint_from_bits(uint32_t bits, uint32_t span) {
    uint32_t mult = 65536u % span;
    mult = (uint32_t)(mult * mult) % span;
    uint32_t hi = bits >> 16, lo = bits & 0xFFFFu;
    uint32_t off = (hi % span) * mult + (lo % span);
    return off % span;
}

__device__ __forceinline__ uint32_t f2bf_rne(float f) {
    uint32_t u = __float_as_uint(f);
    return (u + 0x7FFFu + ((u >> 16) & 1u)) >> 16;
}
__device__ __forceinline__ float bf2f(uint32_t b) {
    return __uint_as_float(b << 16);
}

// ---------------- K0: esq + pre-split/pre-swizzled embedding ----------------
// emb_split global layout: tile (16 codes) = 8192 B; within tile, code cl, dim d:
//   hi at ((cl*512 + d*2) ^ ((cl&7)<<4)), lo at ((cl*512 + 256 + d*2) ^ ((cl&7)<<4))
// so K1 can stage tiles with LINEAR copies and read with the same XOR swizzle.
__global__ void k0_prep(const float* __restrict__ emb, float* __restrict__ esq,
                        char* __restrict__ embs) {
    int k = blockIdx.x, d = threadIdx.x; // 512 x 128
    float v = emb[k * DDIM + d];
    uint32_t hb = f2bf_rne(v);
    float hf = bf2f(hb);
    uint32_t lb = f2bf_rne(v - hf);
    char* base = embs + (size_t)(k >> 4) * 8192;
    int cl = k & 15, sw = (cl & 7) << 4;
    *(unsigned short*)(base + (((cl * 512) + d * 2) ^ sw)) = (unsigned short)hb;
    *(unsigned short*)(base + (((cl * 512) + 256 + d * 2) ^ sw)) = (unsigned short)lb;
    // esq from exact f32 (shift per-code distances; keep accurate)
    float s = v * v;
#pragma unroll
    for (int o = 32; o > 0; o >>= 1) s += __shfl_down(s, o);
    __shared__ float p2[2];
    if ((d & 63) == 0) p2[d >> 6] = s;
    __syncthreads();
    if (d == 0) esq[k] = p2[0] + p2[1];
}

// ---------------- K1: MFMA distances + windowed-exact argmin + epilogue ----------------
__global__ __launch_bounds__(256) void k1_mfma(
    const float* __restrict__ x, const float* __restrict__ emb,
    const char* __restrict__ embs, const float* __restrict__ esq,
    float* __restrict__ out_q, float* __restrict__ out_idx_f,
    float* __restrict__ ws_dw, int* __restrict__ ws_cnt,
    float* __restrict__ ws_sc) {

    __shared__ char  XsB[TMR * 512];   // 64 KB: row stride 512B = hi[128]b16 | lo[128]b16, XOR swz
    __shared__ char  EsB[8192];        // 8 KB: one code tile (16 codes x 512B), pre-swizzled
    __shared__ float xsq_s[TMR];
    __shared__ float esq_s[KCODE];
    __shared__ int   idxf[TMR];
    __shared__ int   flags[TMR];
    __shared__ int   nflag;

    const int t = threadIdx.x;
    const int l = t & 63, w = t >> 6;
    const int rowbase = blockIdx.x * TMR;

    if (t == 0) nflag = 0;
    for (int i = t; i < TMR; i += 256) xsq_s[i] = 0.0f;
    for (int i = t; i < KCODE; i += 256) esq_s[i] = esq[i];
    __syncthreads();

    // ---- stage X: f32 -> (hi,lo) bf16 swizzled + xsq (reconstructed) via LDS atomics
    {
        const float4* xs4 = (const float4*)(x + (size_t)rowbase * DDIM);
#pragma unroll
        for (int j = 0; j < 16; ++j) {
            int i = t + 256 * j;                 // float4 index 0..4095
            float4 v = xs4[i];
            int row = i >> 5, d0 = (i & 31) * 4;
            float f[4] = {v.x, v.y, v.z, v.w};
            unsigned long long hp = 0ull, lp = 0ull;
            float rsum = 0.0f;
#pragma unroll
            for (int e = 0; e < 4; ++e) {
                uint32_t hb = f2bf_rne(f[e]);
                float hf = bf2f(hb);
                float lo = f[e] - hf;
                uint32_t lb = f2bf_rne(lo);
                float rec = hf + bf2f(lb);
                rsum = fmaf(rec, rec, rsum);
                hp |= (unsigned long long)(hb & 0xFFFFu) << (16 * e);
                lp |= (unsigned long long)(lb & 0xFFFFu) << (16 * e);
            }
            int sw = (row & 7) << 4;
            *(unsigned long long*)(XsB + ((row * 512 + d0 * 2) ^ sw)) = hp;
            *(unsigned long long*)(XsB + ((row * 512 + 256 + d0 * 2) ^ sw)) = lp;
            atomicAdd(&xsq_s[row], rsum);
        }
    }
    __syncthreads();

    // ---- A fragments register-resident: wave w owns rows w*32 .. w*32+31
    short8 afrag[2][2][4];   // [seg hi/lo][rowgroup][k-chunk]
#pragma unroll
    for (int rg = 0; rg < 2; ++rg) {
        int row = w * 32 + rg * 16 + (l & 15);
        int sw = (row & 7) << 4;
#pragma unroll
        for (int c = 0; c < 4; ++c) {
            int off = row * 512 + 64 * c + 16 * (l >> 4);
            afrag[0][rg][c] = *(const short8*)(XsB + (off ^ sw));
            afrag[1][rg][c] = *(const short8*)(XsB + ((off + 256) ^ sw));
        }
    }
    float xq[2][4];
#pragma unroll
    for (int rg = 0; rg < 2; ++rg)
#pragma unroll
        for (int r = 0; r < 4; ++r)
            xq[rg][r] = xsq_s[w * 32 + rg * 16 + (l >> 4) * 4 + r];

    float m1[2][4], m2[2][4];
    int   i1[2][4];
#pragma unroll
    for (int rg = 0; rg < 2; ++rg)
#pragma unroll
        for (int r = 0; r < 4; ++r) { m1[rg][r] = 3.4e38f; m2[rg][r] = 3.4e38f; i1[rg][r] = 0; }

    const int cl = l & 15;
    const int bsw = (cl & 7) << 4;
    const int boff0 = cl * 512 + 16 * (l >> 4);

#define PROC_TILE(CT)                                                            \
    {                                                                            \
        short8 bh[4], bl[4];                                                     \
        _Pragma("unroll")                                                        \
        for (int c = 0; c < 4; ++c) {                                            \
            bh[c] = *(const short8*)(EsB + ((boff0 + 64 * c) ^ bsw));            \
            bl[c] = *(const short8*)(EsB + ((boff0 + 256 + 64 * c) ^ bsw));      \
        }                                                                        \
        f32x4 accA = {0.f, 0.f, 0.f, 0.f}, accB = {0.f, 0.f, 0.f, 0.f};          \
        _Pragma("unroll")                                                        \
        for (int c = 0; c < 4; ++c) {                                            \
            accA = __builtin_amdgcn_mfma_f32_16x16x32_bf16(afrag[0][0][c], bh[c], accA, 0, 0, 0); \
            accB = __builtin_amdgcn_mfma_f32_16x16x32_bf16(afrag[0][1][c], bh[c], accB, 0, 0, 0); \
            accA = __builtin_amdgcn_mfma_f32_16x16x32_bf16(afrag[1][0][c], bh[c], accA, 0, 0, 0); \
            accB = __builtin_amdgcn_mfma_f32_16x16x32_bf16(afrag[1][1][c], bh[c], accB, 0, 0, 0); \
            accA = __builtin_amdgcn_mfma_f32_16x16x32_bf16(afrag[0][0][c], bl[c], accA, 0, 0, 0); \
            accB = __builtin_amdgcn_mfma_f32_16x16x32_bf16(afrag[0][1][c], bl[c], accB, 0, 0, 0); \
        }                                                                        \
        int code = (CT) * 16 + cl;                                               \
        float ec = esq_s[code];                                                  \
        _Pragma("unroll")                                                        \
        for (int r = 0; r < 4; ++r) {                                            \
            float v0 = fmaf(-2.0f, accA[r], xq[0][r] + ec);                      \
            bool lt0 = v0 < m1[0][r];                                            \
            m2[0][r] = fminf(m2[0][r], lt0 ? m1[0][r] : v0);                     \
            i1[0][r] = lt0 ? code : i1[0][r];                                    \
            m1[0][r] = lt0 ? v0 : m1[0][r];                                      \
            float v1 = fmaf(-2.0f, accB[r], xq[1][r] + ec);                      \
            bool lt1 = v1 < m1[1][r];                                            \
            m2[1][r] = fminf(m2[1][r], lt1 ? m1[1][r] : v1);                     \
            i1[1][r] = lt1 ? code : i1[1][r];                                    \
            m1[1][r] = lt1 ? v1 : m1[1][r];                                      \
        }                                                                        \
    }

    // ---- main loop over 32 code tiles, single Es buffer, issue-early prefetch
    float4 pA0, pA1, pB0, pB1;
    pA0 = *(const float4*)(embs + 0 * 8192 + t * 32);
    pA1 = *(const float4*)(embs + 0 * 8192 + t * 32 + 16);
    for (int ct2 = 0; ct2 < NCT / 2; ++ct2) {
        int ta = 2 * ct2, tb = 2 * ct2 + 1;
        __syncthreads();
        *(float4*)(EsB + t * 32) = pA0;
        *(float4*)(EsB + t * 32 + 16) = pA1;
        pB0 = *(const float4*)(embs + (size_t)tb * 8192 + t * 32);
        pB1 = *(const float4*)(embs + (size_t)tb * 8192 + t * 32 + 16);
        __syncthreads();
        PROC_TILE(ta);
        __syncthreads();
        *(float4*)(EsB + t * 32) = pB0;
        *(float4*)(EsB + t * 32 + 16) = pB1;
        if (tb + 1 < NCT) {
            pA0 = *(const float4*)(embs + (size_t)(tb + 1) * 8192 + t * 32);
            pA1 = *(const float4*)(embs + (size_t)(tb + 1) * 8192 + t * 32 + 16);
        }
        __syncthreads();
        PROC_TILE(tb);
    }
#undef PROC_TILE

    // ---- cross-lane top-2 merge over the 16 code-lanes
#pragma unroll
    for (int xm = 1; xm <= 8; xm <<= 1) {
#pragma unroll
        for (int rg = 0; rg < 2; ++rg)
#pragma unroll
            for (int r = 0; r < 4; ++r) {
                float om1 = __shfl_xor(m1[rg][r], xm);
                int   oi1 = __shfl_xor(i1[rg][r], xm);
                float om2 = __shfl_xor(m2[rg][r], xm);
                bool swp = (om1 < m1[rg][r]) || (om1 == m1[rg][r] && oi1 < i1[rg][r]);
                float big = swp ? m1[rg][r] : om1;
                m2[rg][r] = fminf(fminf(m2[rg][r], om2), big);
                m1[rg][r] = swp ? om1 : m1[rg][r];
                i1[rg][r] = swp ? oi1 : i1[rg][r];
            }
    }
    if ((l & 15) == 0) {
#pragma unroll
        for (int rg = 0; rg < 2; ++rg)
#pragma unroll
            for (int r = 0; r < 4; ++r) {
                int row = w * 32 + rg * 16 + (l >> 4) * 4 + r;
                idxf[row] = i1[rg][r];
                if (m2[rg][r] - m1[rg][r] < EPS_W) {
                    int p = atomicAdd(&nflag, 1);
                    flags[p] = row;
                }
            }
    }
    __syncthreads();

    // ---- exact f32 fallback for flagged (near-tie) rows; one wave per row
    {
        int nf = nflag;
        for (int f = w; f < nf; f += 4) {
            int row = flags[f];
            const float* xr = x + (size_t)(rowbase + row) * DDIM;
            float part = xr[l] * xr[l] + xr[l + 64] * xr[l + 64];
#pragma unroll
            for (int o = 32; o > 0; o >>= 1) part += __shfl_xor(part, o);
            float bv = 3.4e38f; int bi = 0;
            for (int j = 0; j < 8; ++j) {
                int code = l + 64 * j;
                const float* er = emb + code * DDIM;
                float acc = 0.0f;
#pragma unroll 8
                for (int d = 0; d < DDIM; ++d) acc = fmaf(xr[d], er[d], acc);
                float t1 = part + esq_s[code];
                float v = t1 - 2.0f * acc;
                if (v < bv) { bv = v; bi = code; }
            }
#pragma unroll
            for (int o = 32; o > 0; o >>= 1) {
                float ov = __shfl_xor(bv, o); int oi = __shfl_xor(bi, o);
                if (ov < bv || (ov == bv && oi < bi)) { bv = ov; bi = oi; }
            }
            if (l == 0) idxf[row] = bi;
        }
    }
    __syncthreads();

    // ---- epilogue: indices, counts, quantize+ST, loss, dw scatter
    if (t < TMR) {
        int mi = idxf[t];
        out_idx_f[rowbase + t] = (float)mi;
        atomicAdd(&ws_cnt[mi], 1);
    }
    float lacc = 0.0f;
#pragma unroll
    for (int j = 0; j < 16; ++j) {
        int i = t + 256 * j;
        int row = i >> 5, d0 = (i & 31) * 4;
        int ci = idxf[row];
        float4 q = *(const float4*)(emb + ci * DDIM + d0);
        int sw = (row & 7) << 4;
        unsigned long long hp = *(const unsigned long long*)(XsB + ((row * 512 + d0 * 2) ^ sw));
        unsigned long long lp = *(const unsigned long long*)(XsB + ((row * 512 + 256 + d0 * 2) ^ sw));
        float qf[4] = {q.x, q.y, q.z, q.w};
        float o[4];
#pragma unroll
        for (int e = 0; e < 4; ++e) {
            float xr = bf2f((uint32_t)((hp >> (16 * e)) & 0xFFFFu))
                     + bf2f((uint32_t)((lp >> (16 * e)) & 0xFFFFu));
            float df = qf[e] - xr;
            o[e] = xr + df;
            lacc = fmaf(df, df, lacc);
            atomicAdd(&ws_dw[ci * DDIM + d0 + e], xr);
        }
        float4 ov = {o[0], o[1], o[2], o[3]};
        *(float4*)(out_q + (size_t)(rowbase + row) * DDIM + d0) = ov;
    }
#pragma unroll
    for (int off = 32; off > 0; off >>= 1) lacc += __shfl_down(lacc, off);
    if (l == 0) atomicAdd(&ws_sc[0], lacc);
}

// ---------------- K3: cluster-size EMA+normalize, loss, threefry rand ----------------
__global__ __launch_bounds__(512) void k3_cs(
    const int* __restrict__ ws_cnt, const float* __restrict__ ema_cs,
    const float* __restrict__ ws_sc,
    float* __restrict__ out_loss, float* __restrict__ out_cs,
    float* __restrict__ ws_csn, int* __restrict__ ws_rand) {
    __shared__ float red[8];
    int t = threadIdx.x; // 512
    float raw = 0.99f * ema_cs[t] + 0.01f * (float)ws_cnt[t];
    float s = raw;
#pragma unroll
    for (int o = 32; o > 0; o >>= 1) s += __shfl_down(s, o);
    if ((t & 63) == 0) red[t >> 6] = s;
    __syncthreads();
    float n = red[0] + red[1] + red[2] + red[3] + red[4] + red[5] + red[6] + red[7];
    float csn = (raw + 1e-5f) / (n + 512.0f * 1e-5f) * n;
    ws_csn[t] = csn;
    out_cs[t] = (csn < 1.0f) ? 1.0f : csn;
    if (t < 256) {
        uint32_t o0, o1;
        threefry2x32(0u, 42u, (uint32_t)t, (uint32_t)(t + 256), o0, o1);
        ws_rand[t]       = (int)jax_randint_from_bits(o0, (uint32_t)N_ROWS);
        ws_rand[t + 256] = (int)jax_randint_from_bits(o1, (uint32_t)N_ROWS);
    }
    if (t == 0) out_loss[0] = 0.25f * ws_sc[0] / (float)(N_ROWS * DDIM);
}

// ---------------- K4: EMA update + dead-code reinit ----------------
__global__ void k4_update(const float* __restrict__ ws_dw, const float* __restrict__ ema_w,
                          const float* __restrict__ ws_csn, const int* __restrict__ ws_rand,
                          const float* __restrict__ x,
                          float* __restrict__ out_ne, float* __restrict__ out_nw) {
    int k = blockIdx.x, d = threadIdx.x; // 512 x 128
    float nw = 0.99f * ema_w[k * DDIM + d] + 0.01f * ws_dw[k * DDIM + d];
    float cs = ws_csn[k];
    float ne = nw / cs;
    if (cs < 1.0f) {
        float r = x[(size_t)ws_rand[k] * DDIM + d];
        ne = r; nw = r;
    }
    out_ne[k * DDIM + d] = ne;
    out_nw[k * DDIM + d] = nw;
}

extern "C" void kernel_launch(void* const* d_in, const int* in_sizes, int n_in,
                              void* d_out, int out_size, void* d_ws, size_t ws_size,
                              hipStream_t stream) {
    const float* x      = (const float*)d_in[0]; // [N, 128]
    const float* emb    = (const float*)d_in[1]; // [512, 128]
    const float* ema_cs = (const float*)d_in[2]; // [512]
    const float* ema_w  = (const float*)d_in[3]; // [512, 128]

    float* out = (float*)d_out;
    float* out_q    = out;                       // 16777216
    float* out_loss = out + 16777216;            // 1
    float* out_idx  = out + 16777217;            // 131072
    float* out_ne   = out + 16908289;            // 65536
    float* out_cs   = out + 16973825;            // 512
    float* out_nw   = out + 16974337;            // 65536

    char* w = (char*)d_ws;
    float* ws_dw   = (float*)(w);                 // 262144 B  [zeroed]
    int*   ws_cnt  = (int*)  (w + 262144);        // 2048 B    [zeroed]
    float* ws_sc   = (float*)(w + 264192);        // 64 B      [zeroed]
    float* ws_csn  = (float*)(w + 264256);        // 2048 B
    int*   ws_rand = (int*)  (w + 266304);        // 2048 B
    float* ws_esq  = (float*)(w + 268352);        // 2048 B
    char*  ws_embs = (char*) (w + 270400);        // 393216 B (512x384 bf16, pre-swizzled)

    hipMemsetAsync(d_ws, 0, 264256, stream);      // dw + cnt + sc

    k0_prep<<<KCODE, DDIM, 0, stream>>>(emb, ws_esq, ws_embs);
    k1_mfma<<<N_ROWS / TMR, 256, 0, stream>>>(x, emb, ws_embs, ws_esq,
                                              out_q, out_idx, ws_dw, ws_cnt, ws_sc);
    k3_cs<<<1, 512, 0, stream>>>(ws_cnt, ema_cs, ws_sc, out_loss, out_cs, ws_csn, ws_rand);
    k4_update<<<KCODE, DDIM, 0, stream>>>(ws_dw, ema_w, ws_csn, ws_rand, x, out_ne, out_nw);
}